// Round 1
// baseline (661.717 us; speedup 1.0000x reference)
//
#include <hip/hip_runtime.h>
#include <hip/hip_bf16.h>
#include <stdint.h>

#define T_TOK 1024
#define H_DIM 2048
#define I_DIM 1408
#define E_NUM 16
#define K_TOP 4
#define IS_DIM 2816
#define MAXRT 80   // max row tiles: 4096/64 + 16 = 80

typedef __hip_bfloat16 bf;
typedef __attribute__((ext_vector_type(8))) __bf16 bf16x8;
typedef __attribute__((ext_vector_type(4))) float f32x4;

static_assert(H_DIM % 64 == 0 && I_DIM % 64 == 0 && IS_DIM % 64 == 0, "");

// ---------------- cast hidden states fp32 -> bf16 ----------------
__global__ void cvt_x_kernel(const float* __restrict__ in, bf* __restrict__ out) {
  int i = blockIdx.x * blockDim.x + threadIdx.x;  // indexes float4
  float4 v = reinterpret_cast<const float4*>(in)[i];
  int b = i * 4;
  out[b + 0] = __float2bfloat16(v.x);
  out[b + 1] = __float2bfloat16(v.y);
  out[b + 2] = __float2bfloat16(v.z);
  out[b + 3] = __float2bfloat16(v.w);
}

// ---------------- transpose + cast: in fp32 [R][C] -> out bf16 [C][R], batched z ----------------
__global__ void transpose_cast_kernel(const float* __restrict__ in, bf* __restrict__ out,
                                      int R, int C) {
  long mb = (long)blockIdx.z * R * C;
  const float* ip = in + mb;
  bf* op = out + mb;
  __shared__ float tile[32][33];
  int c0 = blockIdx.x * 32, r0 = blockIdx.y * 32;
  int tx = threadIdx.x, ty = threadIdx.y;  // 32 x 8
#pragma unroll
  for (int j = 0; j < 4; j++)
    tile[ty + 8 * j][tx] = ip[(long)(r0 + ty + 8 * j) * C + (c0 + tx)];
  __syncthreads();
#pragma unroll
  for (int j = 0; j < 4; j++)
    op[(long)(c0 + ty + 8 * j) * R + (r0 + tx)] = __float2bfloat16(tile[tx][ty + 8 * j]);
}

// ---------------- gate: logits (fp32, exact), softmax, top-4 ----------------
__global__ void gate_topk_kernel(const float* __restrict__ x, const float* __restrict__ gw,
                                 int* __restrict__ topk_idx, float* __restrict__ topk_w) {
  int t = blockIdx.x;
  int lane = threadIdx.x;  // 64
  float acc[E_NUM];
#pragma unroll
  for (int e = 0; e < E_NUM; e++) acc[e] = 0.f;
  const float* xt = x + (long)t * H_DIM;
  for (int h = lane; h < H_DIM; h += 64) {
    float xv = xt[h];
#pragma unroll
    for (int e = 0; e < E_NUM; e++) acc[e] += xv * gw[e * H_DIM + h];
  }
#pragma unroll
  for (int e = 0; e < E_NUM; e++) {
    float v = acc[e];
    for (int off = 32; off; off >>= 1) v += __shfl_xor(v, off, 64);
    acc[e] = v;
  }
  if (lane == 0) {
    float m = acc[0];
#pragma unroll
    for (int e = 1; e < E_NUM; e++) m = fmaxf(m, acc[e]);
    float sc[E_NUM];
    float s = 0.f;
#pragma unroll
    for (int e = 0; e < E_NUM; e++) { sc[e] = expf(acc[e] - m); s += sc[e]; }
    float inv = 1.f / s;
#pragma unroll
    for (int e = 0; e < E_NUM; e++) sc[e] *= inv;
    for (int k = 0; k < K_TOP; k++) {
      int bi = 0;
      float bv = sc[0];
      for (int e = 1; e < E_NUM; e++)
        if (sc[e] > bv) { bv = sc[e]; bi = e; }   // strict > : first index wins ties (matches top_k)
      topk_idx[t * K_TOP + k] = bi;
      topk_w[t * K_TOP + k] = bv;
      sc[bi] = -1.f;
    }
  }
}

// ---------------- build per-expert compact token lists, 64-row tiles ----------------
__global__ void build_lists_kernel(const int* __restrict__ topk_idx,
                                   int* __restrict__ rows, int* __restrict__ tile_expert,
                                   int* __restrict__ n_tiles) {
  __shared__ int cnt[E_NUM], cur[E_NUM];
  int tid = threadIdx.x;
  if (tid < E_NUM) cnt[tid] = 0;
  __syncthreads();
  for (int p = tid; p < T_TOK * K_TOP; p += blockDim.x)
    atomicAdd(&cnt[topk_idx[p]], 1);
  __syncthreads();
  if (tid == 0) {
    int tb = 0;
    for (int e = 0; e < E_NUM; e++) {
      int nt = (cnt[e] + 63) >> 6;
      cur[e] = tb * 64;
      for (int j = 0; j < nt; j++) tile_expert[tb + j] = e;
      tb += nt;
    }
    *n_tiles = tb;
  }
  __syncthreads();
  for (int r = tid; r < MAXRT * 64; r += blockDim.x) rows[r] = -1;
  __syncthreads();
  for (int p = tid; p < T_TOK * K_TOP; p += blockDim.x) {
    int e = topk_idx[p];
    int slot = atomicAdd(&cur[e], 1);
    rows[slot] = p;  // p = t*4 + k ; row order within expert is irrelevant (values identical)
  }
}

// ---------------- fused gate+up GEMM: act = silu(X Wg) * (X Wu), bf16 MFMA ----------------
// X rows gathered via rows[] (or dense when rows==nullptr). Wg/Wu are [*][N][H] bf16 (K-contig).
__launch_bounds__(256)
__global__ void gemm_gateup_kernel(const bf* __restrict__ xb,
                                   const int* __restrict__ rows,
                                   const int* __restrict__ tile_expert,
                                   const int* __restrict__ n_tiles,
                                   const bf* __restrict__ Wg,
                                   const bf* __restrict__ Wu,
                                   bf* __restrict__ act, int N) {
  int rt = blockIdx.y;
  if (n_tiles && rt >= *n_tiles) return;
  int e = tile_expert ? tile_expert[rt] : 0;
  long estride = (long)N * H_DIM;
  const bf* wg = Wg + e * estride;
  const bf* wu = Wu + e * estride;
  int i0 = blockIdx.x * 64;

  __shared__ bf16x8 lA[256], lG[256], lU[256];  // 4 fragments each, frag-linear (lane*16B)

  int tid = threadIdx.x;
  int w = tid >> 6, lane = tid & 63;
  int l15 = lane & 15, lhi = lane >> 4;

  int arow = rt * 64 + w * 16 + l15;
  int tok = arow;
  if (rows) { int p = rows[arow]; tok = (p >= 0) ? (p >> 2) : 0; }

  const bf* srcA = xb + (long)tok * H_DIM + lhi * 8;
  const bf* srcG = wg + (long)(i0 + w * 16 + l15) * H_DIM + lhi * 8;
  const bf* srcU = wu + (long)(i0 + w * 16 + l15) * H_DIM + lhi * 8;

  int wr = w >> 1, wc = w & 1;
  f32x4 zero = {0.f, 0.f, 0.f, 0.f};
  f32x4 ag00 = zero, ag01 = zero, ag10 = zero, ag11 = zero;
  f32x4 au00 = zero, au01 = zero, au10 = zero, au11 = zero;

  int sl = w * 64 + lane;
  int ra = wr * 128 + lane;  // A fragments 2wr, 2wr+1
  int rb = wc * 128 + lane;  // B fragments 2wc, 2wc+1

  for (int kt = 0; kt < H_DIM; kt += 32) {
    bf16x8 va = *reinterpret_cast<const bf16x8*>(srcA);
    bf16x8 vg = *reinterpret_cast<const bf16x8*>(srcG);
    bf16x8 vu = *reinterpret_cast<const bf16x8*>(srcU);
    srcA += 32; srcG += 32; srcU += 32;
    __syncthreads();
    lA[sl] = va; lG[sl] = vg; lU[sl] = vu;
    __syncthreads();
    bf16x8 a0 = lA[ra], a1 = lA[ra + 64];
    bf16x8 g0 = lG[rb], g1 = lG[rb + 64];
    bf16x8 u0 = lU[rb], u1 = lU[rb + 64];
    ag00 = __builtin_amdgcn_mfma_f32_16x16x32_bf16(a0, g0, ag00, 0, 0, 0);
    ag01 = __builtin_amdgcn_mfma_f32_16x16x32_bf16(a0, g1, ag01, 0, 0, 0);
    ag10 = __builtin_amdgcn_mfma_f32_16x16x32_bf16(a1, g0, ag10, 0, 0, 0);
    ag11 = __builtin_amdgcn_mfma_f32_16x16x32_bf16(a1, g1, ag11, 0, 0, 0);
    au00 = __builtin_amdgcn_mfma_f32_16x16x32_bf16(a0, u0, au00, 0, 0, 0);
    au01 = __builtin_amdgcn_mfma_f32_16x16x32_bf16(a0, u1, au01, 0, 0, 0);
    au10 = __builtin_amdgcn_mfma_f32_16x16x32_bf16(a1, u0, au10, 0, 0, 0);
    au11 = __builtin_amdgcn_mfma_f32_16x16x32_bf16(a1, u1, au11, 0, 0, 0);
  }

  f32x4 gs[2][2] = {{ag00, ag01}, {ag10, ag11}};
  f32x4 us[2][2] = {{au00, au01}, {au10, au11}};
  int rbase = rt * 64 + wr * 32;
  int cbase = i0 + wc * 32;
#pragma unroll
  for (int fm = 0; fm < 2; fm++)
#pragma unroll
    for (int fn = 0; fn < 2; fn++) {
#pragma unroll
      for (int r = 0; r < 4; r++) {
        float gv = gs[fm][fn][r];
        float uv = us[fm][fn][r];
        float s = (gv / (1.f + __expf(-gv))) * uv;  // silu(g)*u
        int row = rbase + fm * 16 + lhi * 4 + r;    // D: row=(lane>>4)*4+reg
        int col = cbase + fn * 16 + l15;            //    col=lane&15   [m89]
        act[(long)row * N + col] = __float2bfloat16(s);
      }
    }
}

// ---------------- down GEMM: out = act @ Wd^T(layout [*][H][Kin]) ----------------
__launch_bounds__(256)
__global__ void gemm_down_kernel(const bf* __restrict__ A,
                                 const int* __restrict__ rows,
                                 const int* __restrict__ tile_expert,
                                 const int* __restrict__ n_tiles,
                                 const bf* __restrict__ Wd,
                                 bf* __restrict__ outbuf, int Kin) {
  int rt = blockIdx.y;
  if (n_tiles && rt >= *n_tiles) return;
  int e = tile_expert ? tile_expert[rt] : 0;
  const bf* wd = Wd + (long)e * H_DIM * Kin;
  int h0 = blockIdx.x * 64;

  __shared__ bf16x8 lA[256], lB[256];
  __shared__ int rowsl[64];

  int tid = threadIdx.x;
  int w = tid >> 6, lane = tid & 63;
  int l15 = lane & 15, lhi = lane >> 4;
  if (rows && tid < 64) rowsl[tid] = rows[rt * 64 + tid];

  const bf* srcA = A + (long)(rt * 64 + w * 16 + l15) * Kin + lhi * 8;
  const bf* srcB = wd + (long)(h0 + w * 16 + l15) * Kin + lhi * 8;

  int wr = w >> 1, wc = w & 1;
  f32x4 zero = {0.f, 0.f, 0.f, 0.f};
  f32x4 c00 = zero, c01 = zero, c10 = zero, c11 = zero;
  int sl = w * 64 + lane, ra = wr * 128 + lane, rb = wc * 128 + lane;

  for (int kt = 0; kt < Kin; kt += 32) {
    bf16x8 va = *reinterpret_cast<const bf16x8*>(srcA);
    bf16x8 vb = *reinterpret_cast<const bf16x8*>(srcB);
    srcA += 32; srcB += 32;
    __syncthreads();
    lA[sl] = va; lB[sl] = vb;
    __syncthreads();
    bf16x8 a0 = lA[ra], a1 = lA[ra + 64];
    bf16x8 b0 = lB[rb], b1 = lB[rb + 64];
    c00 = __builtin_amdgcn_mfma_f32_16x16x32_bf16(a0, b0, c00, 0, 0, 0);
    c01 = __builtin_amdgcn_mfma_f32_16x16x32_bf16(a0, b1, c01, 0, 0, 0);
    c10 = __builtin_amdgcn_mfma_f32_16x16x32_bf16(a1, b0, c10, 0, 0, 0);
    c11 = __builtin_amdgcn_mfma_f32_16x16x32_bf16(a1, b1, c11, 0, 0, 0);
  }

  f32x4 cs[2][2] = {{c00, c01}, {c10, c11}};
  int cbase = h0 + wc * 32;
#pragma unroll
  for (int fm = 0; fm < 2; fm++)
#pragma unroll
    for (int fn = 0; fn < 2; fn++) {
#pragma unroll
      for (int r = 0; r < 4; r++) {
        int lrow = wr * 32 + fm * 16 + lhi * 4 + r;
        int col = cbase + fn * 16 + l15;
        float v = cs[fm][fn][r];
        if (rows) {
          int p = rowsl[lrow];
          if (p >= 0) outbuf[(long)p * H_DIM + col] = __float2bfloat16(v);
        } else {
          outbuf[(long)(rt * 64 + lrow) * H_DIM + col] = __float2bfloat16(v);
        }
      }
    }
}

// ---------------- combine: out = shared + sum_k w_k * pair_k (fixed order => deterministic) ----
__global__ void combine_kernel(const bf* __restrict__ out_pair,
                               const bf* __restrict__ shared_out,
                               const float* __restrict__ topk_w,
                               float* __restrict__ out) {
  int idx = blockIdx.x * blockDim.x + threadIdx.x;
  int t = idx >> 11;   // H_DIM = 2048
  int h = idx & 2047;
  float acc = __bfloat162float(shared_out[idx]);
#pragma unroll
  for (int k = 0; k < 4; k++)
    acc += topk_w[t * 4 + k] * __bfloat162float(out_pair[(long)(t * 4 + k) * H_DIM + h]);
  out[idx] = acc;
}

extern "C" void kernel_launch(void* const* d_in, const int* in_sizes, int n_in,
                              void* d_out, int out_size, void* d_ws, size_t ws_size,
                              hipStream_t stream) {
  const float* x     = (const float*)d_in[0];
  const float* gw    = (const float*)d_in[1];
  const float* wgate = (const float*)d_in[2];
  const float* wup   = (const float*)d_in[3];
  const float* wdown = (const float*)d_in[4];
  const float* swg   = (const float*)d_in[5];
  const float* swu   = (const float*)d_in[6];
  const float* swd   = (const float*)d_in[7];
  float* out = (float*)d_out;

  char* ws = (char*)d_ws;
  size_t off = 0;
  auto alloc = [&](size_t bytes) {
    void* p = ws + off;
    off += (bytes + 255) & ~(size_t)255;
    return p;
  };

  bf* xb   = (bf*)alloc((size_t)T_TOK * H_DIM * 2);
  bf* wgT  = (bf*)alloc((size_t)E_NUM * I_DIM * H_DIM * 2);   // [E][I][H]
  bf* wuT  = (bf*)alloc((size_t)E_NUM * I_DIM * H_DIM * 2);   // [E][I][H]
  bf* wdT  = (bf*)alloc((size_t)E_NUM * H_DIM * I_DIM * 2);   // [E][H][I]
  bf* swgT = (bf*)alloc((size_t)IS_DIM * H_DIM * 2);          // [IS][H]
  bf* swuT = (bf*)alloc((size_t)IS_DIM * H_DIM * 2);          // [IS][H]
  bf* swdT = (bf*)alloc((size_t)H_DIM * IS_DIM * 2);          // [H][IS]
  bf* act  = (bf*)alloc((size_t)MAXRT * 64 * I_DIM * 2);      // padded-row space
  bf* sact = (bf*)alloc((size_t)T_TOK * IS_DIM * 2);
  bf* outp = (bf*)alloc((size_t)T_TOK * K_TOP * H_DIM * 2);   // per (t,k) expert output
  bf* sout = (bf*)alloc((size_t)T_TOK * H_DIM * 2);
  int*   topk_idx = (int*)alloc(T_TOK * K_TOP * 4);
  float* topk_w   = (float*)alloc(T_TOK * K_TOP * 4);
  int*   rowsbuf  = (int*)alloc(MAXRT * 64 * 4);
  int*   tile_exp = (int*)alloc(MAXRT * 4);
  int*   n_tiles  = (int*)alloc(64);
  (void)ws_size; (void)in_sizes; (void)n_in; (void)out_size;

  hipLaunchKernelGGL(cvt_x_kernel, dim3(T_TOK * H_DIM / 1024), dim3(256), 0, stream, x, xb);
  hipLaunchKernelGGL(gate_topk_kernel, dim3(T_TOK), dim3(64), 0, stream, x, gw, topk_idx, topk_w);
  hipLaunchKernelGGL(build_lists_kernel, dim3(1), dim3(256), 0, stream, topk_idx, rowsbuf, tile_exp, n_tiles);

  dim3 tb(32, 8);
  hipLaunchKernelGGL(transpose_cast_kernel, dim3(I_DIM / 32, H_DIM / 32, E_NUM), tb, 0, stream, wgate, wgT, H_DIM, I_DIM);
  hipLaunchKernelGGL(transpose_cast_kernel, dim3(I_DIM / 32, H_DIM / 32, E_NUM), tb, 0, stream, wup,   wuT, H_DIM, I_DIM);
  hipLaunchKernelGGL(transpose_cast_kernel, dim3(H_DIM / 32, I_DIM / 32, E_NUM), tb, 0, stream, wdown, wdT, I_DIM, H_DIM);
  hipLaunchKernelGGL(transpose_cast_kernel, dim3(IS_DIM / 32, H_DIM / 32, 1), tb, 0, stream, swg, swgT, H_DIM, IS_DIM);
  hipLaunchKernelGGL(transpose_cast_kernel, dim3(IS_DIM / 32, H_DIM / 32, 1), tb, 0, stream, swu, swuT, H_DIM, IS_DIM);
  hipLaunchKernelGGL(transpose_cast_kernel, dim3(H_DIM / 32, IS_DIM / 32, 1), tb, 0, stream, swd, swdT, IS_DIM, H_DIM);

  // routed gate+up  -> act (bf16)
  hipLaunchKernelGGL(gemm_gateup_kernel, dim3(I_DIM / 64, MAXRT), dim3(256), 0, stream,
                     xb, rowsbuf, tile_exp, n_tiles, wgT, wuT, act, I_DIM);
  // shared gate+up  -> sact
  hipLaunchKernelGGL(gemm_gateup_kernel, dim3(IS_DIM / 64, T_TOK / 64), dim3(256), 0, stream,
                     xb, nullptr, nullptr, nullptr, swgT, swuT, sact, IS_DIM);
  // routed down -> out_pair
  hipLaunchKernelGGL(gemm_down_kernel, dim3(H_DIM / 64, MAXRT), dim3(256), 0, stream,
                     act, rowsbuf, tile_exp, n_tiles, wdT, outp, I_DIM);
  // shared down -> sout
  hipLaunchKernelGGL(gemm_down_kernel, dim3(H_DIM / 64, T_TOK / 64), dim3(256), 0, stream,
                     sact, nullptr, nullptr, nullptr, swdT, sout, IS_DIM);

  hipLaunchKernelGGL(combine_kernel, dim3(T_TOK * H_DIM / 256), dim3(256), 0, stream,
                     outp, sout, topk_w, out);
}

// Round 2
// 525.573 us; speedup vs baseline: 1.2590x; 1.2590x over previous
//
#include <hip/hip_runtime.h>
#include <hip/hip_bf16.h>
#include <stdint.h>

#define T_TOK 1024
#define H_DIM 2048
#define I_DIM 1408
#define E_NUM 16
#define K_TOP 4
#define IS_DIM 2816
#define BM 128
#define BN 128
#define BK 64
#define MAXRT 48   // max 128-row tiles: 4096/128 + 16 = 48

typedef __hip_bfloat16 bf;
typedef __attribute__((ext_vector_type(8))) __bf16 bf16x8;
typedef __attribute__((ext_vector_type(4))) float f32x4;

// async global->LDS, 16B per lane; LDS dest is wave-uniform base + lane*16
__device__ __forceinline__ void gload16(const void* g, void* l) {
  __builtin_amdgcn_global_load_lds((const __attribute__((address_space(1))) void*)g,
                                   (__attribute__((address_space(3))) void*)l, 16, 0, 0);
}

// ---------------- cast hidden states fp32 -> bf16 ----------------
__global__ void cvt_x_kernel(const float* __restrict__ in, bf* __restrict__ out) {
  int i = blockIdx.x * blockDim.x + threadIdx.x;  // indexes float4
  float4 v = reinterpret_cast<const float4*>(in)[i];
  int b = i * 4;
  out[b + 0] = __float2bfloat16(v.x);
  out[b + 1] = __float2bfloat16(v.y);
  out[b + 2] = __float2bfloat16(v.z);
  out[b + 3] = __float2bfloat16(v.w);
}

// ---------------- transpose + cast: in fp32 [R][C] -> out bf16 [C][R], batched z ----------------
// 64x64 tiles, float4 loads, bf16x8 stores
__global__ void transpose_cast_kernel(const float* __restrict__ in, bf* __restrict__ out,
                                      int R, int C) {
  long mb = (long)blockIdx.z * R * C;
  const float* ip = in + mb;
  bf* op = out + mb;
  __shared__ float t[64][65];
  int r0 = blockIdx.y * 64, c0 = blockIdx.x * 64;
  int tid = threadIdx.x;  // 256
  int q = tid & 15, r = tid >> 4;
  const float* src = ip + (long)(r0 + r) * C + c0 + q * 4;
#pragma unroll
  for (int j = 0; j < 4; j++) {
    float4 v = *reinterpret_cast<const float4*>(src + (long)16 * j * C);
    t[r + 16 * j][q * 4 + 0] = v.x;
    t[r + 16 * j][q * 4 + 1] = v.y;
    t[r + 16 * j][q * 4 + 2] = v.z;
    t[r + 16 * j][q * 4 + 3] = v.w;
  }
  __syncthreads();
  int c = tid >> 2, g = tid & 3;
#pragma unroll
  for (int u = 0; u < 2; u++) {
    int rg = g + 4 * u;
    union { bf16x8 v; bf s[8]; } o;
#pragma unroll
    for (int j = 0; j < 8; j++) o.s[j] = __float2bfloat16(t[rg * 8 + j][c]);
    *reinterpret_cast<bf16x8*>(op + (long)(c0 + c) * R + r0 + rg * 8) = o.v;
  }
}

// ---------------- gate: logits (fp32, exact), softmax, top-4 ----------------
__global__ void gate_topk_kernel(const float* __restrict__ x, const float* __restrict__ gw,
                                 int* __restrict__ topk_idx, float* __restrict__ topk_w) {
  int t = blockIdx.x;
  int lane = threadIdx.x;  // 64
  float acc[E_NUM];
#pragma unroll
  for (int e = 0; e < E_NUM; e++) acc[e] = 0.f;
  const float* xt = x + (long)t * H_DIM;
  for (int h = lane; h < H_DIM; h += 64) {
    float xv = xt[h];
#pragma unroll
    for (int e = 0; e < E_NUM; e++) acc[e] += xv * gw[e * H_DIM + h];
  }
#pragma unroll
  for (int e = 0; e < E_NUM; e++) {
    float v = acc[e];
    for (int off = 32; off; off >>= 1) v += __shfl_xor(v, off, 64);
    acc[e] = v;
  }
  if (lane == 0) {
    float m = acc[0];
#pragma unroll
    for (int e = 1; e < E_NUM; e++) m = fmaxf(m, acc[e]);
    float sc[E_NUM];
    float s = 0.f;
#pragma unroll
    for (int e = 0; e < E_NUM; e++) { sc[e] = expf(acc[e] - m); s += sc[e]; }
    float inv = 1.f / s;
#pragma unroll
    for (int e = 0; e < E_NUM; e++) sc[e] *= inv;
    for (int k = 0; k < K_TOP; k++) {
      int bi = 0;
      float bv = sc[0];
      for (int e = 1; e < E_NUM; e++)
        if (sc[e] > bv) { bv = sc[e]; bi = e; }   // strict > : first index wins ties
      topk_idx[t * K_TOP + k] = bi;
      topk_w[t * K_TOP + k] = bv;
      sc[bi] = -1.f;
    }
  }
}

// ---------------- build per-expert compact token lists, 128-row tiles ----------------
__global__ void build_lists_kernel(const int* __restrict__ topk_idx,
                                   int* __restrict__ rows, int* __restrict__ tile_expert,
                                   int* __restrict__ n_tiles) {
  __shared__ int cnt[E_NUM], cur[E_NUM];
  int tid = threadIdx.x;
  if (tid < E_NUM) cnt[tid] = 0;
  __syncthreads();
  for (int p = tid; p < T_TOK * K_TOP; p += blockDim.x)
    atomicAdd(&cnt[topk_idx[p]], 1);
  __syncthreads();
  if (tid == 0) {
    int tb = 0;
    for (int e = 0; e < E_NUM; e++) {
      int nt = (cnt[e] + BM - 1) / BM;
      cur[e] = tb * BM;
      for (int j = 0; j < nt; j++) tile_expert[tb + j] = e;
      tb += nt;
    }
    *n_tiles = tb;
  }
  __syncthreads();
  for (int r = tid; r < MAXRT * BM; r += blockDim.x) rows[r] = -1;
  __syncthreads();
  for (int p = tid; p < T_TOK * K_TOP; p += blockDim.x) {
    int e = topk_idx[p];
    int slot = atomicAdd(&cur[e], 1);
    rows[slot] = p;  // p = t*4 + k ; slot order within expert irrelevant (values identical)
  }
}

// ---------------- fused gate+up GEMM: act = silu(X Wg) * (X Wu), 128x128 tile ----------------
// Wg/Wu layouts: [*][N][H] bf16 (K=H contiguous). A rows gathered via rows[] when non-null.
__launch_bounds__(256, 2)
__global__ void gemm_gateup_kernel(const bf* __restrict__ xb,
                                   const int* __restrict__ rows,
                                   const int* __restrict__ tile_expert,
                                   const int* __restrict__ n_tiles,
                                   const bf* __restrict__ Wg,
                                   const bf* __restrict__ Wu,
                                   bf* __restrict__ act, int N) {
  int rt = blockIdx.y;
  if (n_tiles && rt >= *n_tiles) return;
  int e = tile_expert ? tile_expert[rt] : 0;
  long estride = (long)N * H_DIM;
  const bf* wg = Wg + e * estride;
  const bf* wu = Wu + e * estride;
  int i0 = blockIdx.x * BN;

  __shared__ bf lA[BM * BK];   // [row][k] linear
  __shared__ bf lG[BN * BK];
  __shared__ bf lU[BN * BK];

  int tid = threadIdx.x, w = tid >> 6, lane = tid & 63;
  int l15 = lane & 15, lhi = lane >> 4;
  int srow = w * 8 + (lane >> 3);   // staging row within 32-row group
  int schunk = lane & 7;            // 8-elem (16B) chunk within 64-col row

  const bf* asrc[4];
  long woff[4];
#pragma unroll
  for (int i = 0; i < 4; i++) {
    int rr = rt * BM + i * 32 + srow;
    int tok = rr;
    if (rows) { int p = rows[rr]; tok = (p >= 0) ? (p >> 2) : 0; }
    asrc[i] = xb + (long)tok * H_DIM + schunk * 8;
    woff[i] = (long)(i0 + i * 32 + srow) * H_DIM + schunk * 8;
  }

  f32x4 accg[4][4], accu[4][4];
  f32x4 z4 = {0.f, 0.f, 0.f, 0.f};
#pragma unroll
  for (int m = 0; m < 4; m++)
#pragma unroll
    for (int n = 0; n < 4; n++) { accg[m][n] = z4; accu[m][n] = z4; }

  int wr = w >> 1, wc = w & 1;
  for (int kt = 0; kt < H_DIM; kt += BK) {
    __syncthreads();  // previous tile fully consumed
#pragma unroll
    for (int i = 0; i < 4; i++) {
      int db = (i * 32 + w * 8) * BK;
      gload16(asrc[i] + kt, lA + db);
      gload16(wg + woff[i] + kt, lG + db);
      gload16(wu + woff[i] + kt, lU + db);
    }
    __syncthreads();  // drains vmcnt -> LDS ready
#pragma unroll
    for (int kk = 0; kk < 2; kk++) {
      bf16x8 af[4];
#pragma unroll
      for (int m = 0; m < 4; m++)
        af[m] = *reinterpret_cast<const bf16x8*>(lA + (wr * 64 + m * 16 + l15) * BK + kk * 32 + lhi * 8);
#pragma unroll
      for (int n = 0; n < 4; n++) {
        bf16x8 gf = *reinterpret_cast<const bf16x8*>(lG + (wc * 64 + n * 16 + l15) * BK + kk * 32 + lhi * 8);
        bf16x8 uf = *reinterpret_cast<const bf16x8*>(lU + (wc * 64 + n * 16 + l15) * BK + kk * 32 + lhi * 8);
#pragma unroll
        for (int m = 0; m < 4; m++) {
          accg[m][n] = __builtin_amdgcn_mfma_f32_16x16x32_bf16(af[m], gf, accg[m][n], 0, 0, 0);
          accu[m][n] = __builtin_amdgcn_mfma_f32_16x16x32_bf16(af[m], uf, accu[m][n], 0, 0, 0);
        }
      }
    }
  }

#pragma unroll
  for (int m = 0; m < 4; m++)
#pragma unroll
    for (int n = 0; n < 4; n++)
#pragma unroll
      for (int r2 = 0; r2 < 4; r2++) {
        float gv = accg[m][n][r2];
        float uv = accu[m][n][r2];
        float s = (gv / (1.f + __expf(-gv))) * uv;      // silu(g)*u
        int row = rt * BM + wr * 64 + m * 16 + lhi * 4 + r2;  // C: row=(lane>>4)*4+reg
        int col = i0 + wc * 64 + n * 16 + l15;                //    col=lane&15  [m89]
        act[(long)row * N + col] = __float2bfloat16(s);
      }
}

// ---------------- down GEMM: out = act @ WdT (layout [*][H][Kin]), 128x128 tile ----------------
__launch_bounds__(256, 2)
__global__ void gemm_down_kernel(const bf* __restrict__ A,
                                 const int* __restrict__ rows,
                                 const int* __restrict__ tile_expert,
                                 const int* __restrict__ n_tiles,
                                 const bf* __restrict__ Wd,
                                 bf* __restrict__ outbuf, int Kin) {
  int rt = blockIdx.y;
  if (n_tiles && rt >= *n_tiles) return;
  int e = tile_expert ? tile_expert[rt] : 0;
  const bf* wd = Wd + (long)e * H_DIM * Kin;
  int h0 = blockIdx.x * BN;

  __shared__ bf lA[BM * BK];
  __shared__ bf lB[BN * BK];
  __shared__ int rowsl[BM];

  int tid = threadIdx.x, w = tid >> 6, lane = tid & 63;
  int l15 = lane & 15, lhi = lane >> 4;
  int srow = w * 8 + (lane >> 3);
  int schunk = lane & 7;
  if (rows && tid < BM) rowsl[tid] = rows[rt * BM + tid];

  long aoff[4], boff[4];
#pragma unroll
  for (int i = 0; i < 4; i++) {
    aoff[i] = (long)(rt * BM + i * 32 + srow) * Kin + schunk * 8;
    boff[i] = (long)(h0 + i * 32 + srow) * Kin + schunk * 8;
  }

  f32x4 acc[4][4];
  f32x4 z4 = {0.f, 0.f, 0.f, 0.f};
#pragma unroll
  for (int m = 0; m < 4; m++)
#pragma unroll
    for (int n = 0; n < 4; n++) acc[m][n] = z4;

  int wr = w >> 1, wc = w & 1;
  for (int kt = 0; kt < Kin; kt += BK) {
    __syncthreads();
#pragma unroll
    for (int i = 0; i < 4; i++) {
      int db = (i * 32 + w * 8) * BK;
      gload16(A + aoff[i] + kt, lA + db);
      gload16(wd + boff[i] + kt, lB + db);
    }
    __syncthreads();
#pragma unroll
    for (int kk = 0; kk < 2; kk++) {
      bf16x8 af[4];
#pragma unroll
      for (int m = 0; m < 4; m++)
        af[m] = *reinterpret_cast<const bf16x8*>(lA + (wr * 64 + m * 16 + l15) * BK + kk * 32 + lhi * 8);
#pragma unroll
      for (int n = 0; n < 4; n++) {
        bf16x8 bfr = *reinterpret_cast<const bf16x8*>(lB + (wc * 64 + n * 16 + l15) * BK + kk * 32 + lhi * 8);
#pragma unroll
        for (int m = 0; m < 4; m++)
          acc[m][n] = __builtin_amdgcn_mfma_f32_16x16x32_bf16(af[m], bfr, acc[m][n], 0, 0, 0);
      }
    }
  }

#pragma unroll
  for (int m = 0; m < 4; m++)
#pragma unroll
    for (int n = 0; n < 4; n++)
#pragma unroll
      for (int r2 = 0; r2 < 4; r2++) {
        int lrow = wr * 64 + m * 16 + lhi * 4 + r2;
        int col = h0 + wc * 64 + n * 16 + l15;
        float v = acc[m][n][r2];
        if (rows) {
          int p = rowsl[lrow];
          if (p >= 0) outbuf[(long)p * H_DIM + col] = __float2bfloat16(v);
        } else {
          outbuf[(long)(rt * BM + lrow) * H_DIM + col] = __float2bfloat16(v);
        }
      }
}

// ---------------- combine: out = shared + sum_k w_k * pair_k (fixed order => deterministic) ----
__global__ void combine_kernel(const bf* __restrict__ out_pair,
                               const bf* __restrict__ shared_out,
                               const float* __restrict__ topk_w,
                               float* __restrict__ out) {
  int idx = blockIdx.x * blockDim.x + threadIdx.x;
  int t = idx >> 11;   // H_DIM = 2048
  int h = idx & 2047;
  float acc = __bfloat162float(shared_out[idx]);
#pragma unroll
  for (int k = 0; k < 4; k++)
    acc += topk_w[t * 4 + k] * __bfloat162float(out_pair[(long)(t * 4 + k) * H_DIM + h]);
  out[idx] = acc;
}

extern "C" void kernel_launch(void* const* d_in, const int* in_sizes, int n_in,
                              void* d_out, int out_size, void* d_ws, size_t ws_size,
                              hipStream_t stream) {
  const float* x     = (const float*)d_in[0];
  const float* gw    = (const float*)d_in[1];
  const float* wgate = (const float*)d_in[2];
  const float* wup   = (const float*)d_in[3];
  const float* wdown = (const float*)d_in[4];
  const float* swg   = (const float*)d_in[5];
  const float* swu   = (const float*)d_in[6];
  const float* swd   = (const float*)d_in[7];
  float* out = (float*)d_out;

  char* ws = (char*)d_ws;
  size_t off = 0;
  auto alloc = [&](size_t bytes) {
    void* p = ws + off;
    off += (bytes + 255) & ~(size_t)255;
    return p;
  };

  bf* xb   = (bf*)alloc((size_t)T_TOK * H_DIM * 2);
  bf* wgT  = (bf*)alloc((size_t)E_NUM * I_DIM * H_DIM * 2);   // [E][I][H]
  bf* wuT  = (bf*)alloc((size_t)E_NUM * I_DIM * H_DIM * 2);   // [E][I][H]
  bf* wdT  = (bf*)alloc((size_t)E_NUM * H_DIM * I_DIM * 2);   // [E][H][I]
  bf* swgT = (bf*)alloc((size_t)IS_DIM * H_DIM * 2);          // [IS][H]
  bf* swuT = (bf*)alloc((size_t)IS_DIM * H_DIM * 2);          // [IS][H]
  bf* swdT = (bf*)alloc((size_t)H_DIM * IS_DIM * 2);          // [H][IS]
  bf* act  = (bf*)alloc((size_t)MAXRT * BM * I_DIM * 2);      // padded-slot rows
  bf* sact = (bf*)alloc((size_t)T_TOK * IS_DIM * 2);
  bf* outp = (bf*)alloc((size_t)T_TOK * K_TOP * H_DIM * 2);   // per (t,k) expert output
  bf* sout = (bf*)alloc((size_t)T_TOK * H_DIM * 2);
  int*   topk_idx = (int*)alloc(T_TOK * K_TOP * 4);
  float* topk_w   = (float*)alloc(T_TOK * K_TOP * 4);
  int*   rowsbuf  = (int*)alloc(MAXRT * BM * 4);
  int*   tile_exp = (int*)alloc(MAXRT * 4);
  int*   n_tiles  = (int*)alloc(64);
  (void)ws_size; (void)in_sizes; (void)n_in; (void)out_size;

  hipLaunchKernelGGL(cvt_x_kernel, dim3(T_TOK * H_DIM / 1024), dim3(256), 0, stream, x, xb);
  hipLaunchKernelGGL(gate_topk_kernel, dim3(T_TOK), dim3(64), 0, stream, x, gw, topk_idx, topk_w);
  hipLaunchKernelGGL(build_lists_kernel, dim3(1), dim3(256), 0, stream, topk_idx, rowsbuf, tile_exp, n_tiles);

  dim3 tb(256);
  hipLaunchKernelGGL(transpose_cast_kernel, dim3(I_DIM / 64, H_DIM / 64, E_NUM), tb, 0, stream, wgate, wgT, H_DIM, I_DIM);
  hipLaunchKernelGGL(transpose_cast_kernel, dim3(I_DIM / 64, H_DIM / 64, E_NUM), tb, 0, stream, wup,   wuT, H_DIM, I_DIM);
  hipLaunchKernelGGL(transpose_cast_kernel, dim3(H_DIM / 64, I_DIM / 64, E_NUM), tb, 0, stream, wdown, wdT, I_DIM, H_DIM);
  hipLaunchKernelGGL(transpose_cast_kernel, dim3(IS_DIM / 64, H_DIM / 64, 1), tb, 0, stream, swg, swgT, H_DIM, IS_DIM);
  hipLaunchKernelGGL(transpose_cast_kernel, dim3(IS_DIM / 64, H_DIM / 64, 1), tb, 0, stream, swu, swuT, H_DIM, IS_DIM);
  hipLaunchKernelGGL(transpose_cast_kernel, dim3(H_DIM / 64, IS_DIM / 64, 1), tb, 0, stream, swd, swdT, IS_DIM, H_DIM);

  // routed gate+up -> act
  hipLaunchKernelGGL(gemm_gateup_kernel, dim3(I_DIM / BN, MAXRT), dim3(256), 0, stream,
                     xb, rowsbuf, tile_exp, n_tiles, wgT, wuT, act, I_DIM);
  // shared gate+up -> sact
  hipLaunchKernelGGL(gemm_gateup_kernel, dim3(IS_DIM / BN, T_TOK / BM), dim3(256), 0, stream,
                     xb, nullptr, nullptr, nullptr, swgT, swuT, sact, IS_DIM);
  // routed down -> outp
  hipLaunchKernelGGL(gemm_down_kernel, dim3(H_DIM / BN, MAXRT), dim3(256), 0, stream,
                     act, rowsbuf, tile_exp, n_tiles, wdT, outp, I_DIM);
  // shared down -> sout
  hipLaunchKernelGGL(gemm_down_kernel, dim3(H_DIM / BN, T_TOK / BM), dim3(256), 0, stream,
                     sact, nullptr, nullptr, nullptr, swdT, sout, IS_DIM);

  hipLaunchKernelGGL(combine_kernel, dim3(T_TOK * H_DIM / 256), dim3(256), 0, stream,
                     outp, sout, topk_w, out);
}

// Round 3
// 461.433 us; speedup vs baseline: 1.4340x; 1.1390x over previous
//
#include <hip/hip_runtime.h>
#include <hip/hip_bf16.h>
#include <stdint.h>

#define T_TOK 1024
#define H_DIM 2048
#define I_DIM 1408
#define E_NUM 16
#define K_TOP 4
#define IS_DIM 2816
#define BM 128
#define BN 128
#define BK 64
#define BKP 72   // padded LDS row stride (elements) for B tiles: breaks bank alias
#define MAXRT 48 // max 128-row tiles: 4096/128 + 16 = 48

typedef __hip_bfloat16 bf;
typedef __attribute__((ext_vector_type(8))) __bf16 bf16x8;
typedef __attribute__((ext_vector_type(4))) float f32x4;

// async global->LDS, 16B per lane; LDS dest is wave-uniform base + lane*16
__device__ __forceinline__ void gload16(const void* g, void* l) {
  __builtin_amdgcn_global_load_lds((const __attribute__((address_space(1))) void*)g,
                                   (__attribute__((address_space(3))) void*)l, 16, 0, 0);
}

// ---------------- cast hidden states fp32 -> bf16 ----------------
__global__ void cvt_x_kernel(const float* __restrict__ in, bf* __restrict__ out) {
  int i = blockIdx.x * blockDim.x + threadIdx.x;  // indexes float4
  float4 v = reinterpret_cast<const float4*>(in)[i];
  int b = i * 4;
  out[b + 0] = __float2bfloat16(v.x);
  out[b + 1] = __float2bfloat16(v.y);
  out[b + 2] = __float2bfloat16(v.z);
  out[b + 3] = __float2bfloat16(v.w);
}

// ---------------- gate: logits (fp32, exact), softmax, top-4 ----------------
__global__ void gate_topk_kernel(const float* __restrict__ x, const float* __restrict__ gw,
                                 int* __restrict__ topk_idx, float* __restrict__ topk_w) {
  int t = blockIdx.x;
  int lane = threadIdx.x;  // 64
  float acc[E_NUM];
#pragma unroll
  for (int e = 0; e < E_NUM; e++) acc[e] = 0.f;
  const float* xt = x + (long)t * H_DIM;
  for (int h = lane; h < H_DIM; h += 64) {
    float xv = xt[h];
#pragma unroll
    for (int e = 0; e < E_NUM; e++) acc[e] += xv * gw[e * H_DIM + h];
  }
#pragma unroll
  for (int e = 0; e < E_NUM; e++) {
    float v = acc[e];
    for (int off = 32; off; off >>= 1) v += __shfl_xor(v, off, 64);
    acc[e] = v;
  }
  if (lane == 0) {
    float m = acc[0];
#pragma unroll
    for (int e = 1; e < E_NUM; e++) m = fmaxf(m, acc[e]);
    float sc[E_NUM];
    float s = 0.f;
#pragma unroll
    for (int e = 0; e < E_NUM; e++) { sc[e] = expf(acc[e] - m); s += sc[e]; }
    float inv = 1.f / s;
#pragma unroll
    for (int e = 0; e < E_NUM; e++) sc[e] *= inv;
    for (int k = 0; k < K_TOP; k++) {
      int bi = 0;
      float bv = sc[0];
      for (int e = 1; e < E_NUM; e++)
        if (sc[e] > bv) { bv = sc[e]; bi = e; }   // strict > : first index wins ties
      topk_idx[t * K_TOP + k] = bi;
      topk_w[t * K_TOP + k] = bv;
      sc[bi] = -1.f;
    }
  }
}

// ---------------- build per-expert compact token lists, 128-row tiles ----------------
__global__ void build_lists_kernel(const int* __restrict__ topk_idx,
                                   int* __restrict__ rows, int* __restrict__ tile_expert,
                                   int* __restrict__ n_tiles) {
  __shared__ int cnt[E_NUM], cur[E_NUM];
  int tid = threadIdx.x;
  if (tid < E_NUM) cnt[tid] = 0;
  __syncthreads();
  for (int p = tid; p < T_TOK * K_TOP; p += blockDim.x)
    atomicAdd(&cnt[topk_idx[p]], 1);
  __syncthreads();
  if (tid == 0) {
    int tb = 0;
    for (int e = 0; e < E_NUM; e++) {
      int nt = (cnt[e] + BM - 1) / BM;
      cur[e] = tb * BM;
      for (int j = 0; j < nt; j++) tile_expert[tb + j] = e;
      tb += nt;
    }
    *n_tiles = tb;
  }
  __syncthreads();
  for (int r = tid; r < MAXRT * BM; r += blockDim.x) rows[r] = -1;
  __syncthreads();
  for (int p = tid; p < T_TOK * K_TOP; p += blockDim.x) {
    int e = topk_idx[p];
    int slot = atomicAdd(&cur[e], 1);
    rows[slot] = p;  // p = t*4 + k ; slot order within expert irrelevant (values identical)
  }
}

// ============ fused gate+up GEMM: act = silu(X Wg) * (X Wu) ============
// A: xb bf16 [T][H] (rows gathered). B: Wg/Wu fp32 NATIVE [H][N] (K-major rows,
// N contiguous) -> reg-staged, cast, transposed into LDS [BN][BKP] bf16.
__launch_bounds__(256, 2)
__global__ void gemm_gateup_kernel(const bf* __restrict__ xb,
                                   const int* __restrict__ rows,
                                   const int* __restrict__ tile_expert,
                                   const int* __restrict__ n_tiles,
                                   const float* __restrict__ Wg,
                                   const float* __restrict__ Wu,
                                   bf* __restrict__ act, int N) {
  int rt = blockIdx.y;
  if (n_tiles && rt >= *n_tiles) return;
  int e = tile_expert ? tile_expert[rt] : 0;
  long estride = (long)H_DIM * N;
  int i0 = blockIdx.x * BN;

  __shared__ bf lA[BM * BK];    // [row][k] linear, source-XOR-swizzled chunks
  __shared__ bf lG[BN * BKP];   // [n][k] padded
  __shared__ bf lU[BN * BKP];

  int tid = threadIdx.x, w = tid >> 6, lane = tid & 63;
  int l15 = lane & 15, lhi = lane >> 4;
  int kg = tid >> 5, ng = tid & 31;           // B staging: k-chunk, n-quad
  int sswz = (((lane & 7) ^ (lane >> 3)) * 8);  // A source chunk offset (elements)

  const bf* asrc[4];
#pragma unroll
  for (int i = 0; i < 4; i++) {
    int rr = rt * BM + i * 32 + w * 8 + (lane >> 3);
    int tok = rr;
    if (rows) { int p = rows[rr]; tok = (p >= 0) ? (p >> 2) : 0; }
    asrc[i] = xb + (long)tok * H_DIM + sswz;
  }

  const float* bg = Wg + (long)e * estride + i0 + ng * 4 + (long)kg * 8 * N;
  const float* bu = Wu + (long)e * estride + i0 + ng * 4 + (long)kg * 8 * N;

  f32x4 accg[4][4], accu[4][4];
  f32x4 z4 = {0.f, 0.f, 0.f, 0.f};
#pragma unroll
  for (int m = 0; m < 4; m++)
#pragma unroll
    for (int n = 0; n < 4; n++) { accg[m][n] = z4; accu[m][n] = z4; }

  int wr = w >> 1, wc = w & 1;
  for (int kt = 0; kt < H_DIM; kt += BK) {
    // issue B loads early: registers only, no LDS hazard -> overlaps barrier drain
    float4 vg[8], vu[8];
    const float* pg = bg + (long)kt * N;
    const float* pu = bu + (long)kt * N;
#pragma unroll
    for (int j = 0; j < 8; j++) vg[j] = *reinterpret_cast<const float4*>(pg + (long)j * N);
#pragma unroll
    for (int j = 0; j < 8; j++) vu[j] = *reinterpret_cast<const float4*>(pu + (long)j * N);
    __syncthreads();  // previous tile fully consumed
#pragma unroll
    for (int i = 0; i < 4; i++)
      gload16(asrc[i] + kt, lA + (i * 32 + w * 8) * BK);
#pragma unroll
    for (int c = 0; c < 4; c++) {
      union { bf16x8 x; bf s[8]; } og, ou;
#pragma unroll
      for (int j = 0; j < 8; j++) {
        og.s[j] = __float2bfloat16(((const float*)&vg[j])[c]);
        ou.s[j] = __float2bfloat16(((const float*)&vu[j])[c]);
      }
      *reinterpret_cast<bf16x8*>(lG + (ng * 4 + c) * BKP + kg * 8) = og.x;
      *reinterpret_cast<bf16x8*>(lU + (ng * 4 + c) * BKP + kg * 8) = ou.x;
    }
    __syncthreads();  // LDS ready (vm + lgkm drained)
#pragma unroll
    for (int kk = 0; kk < 2; kk++) {
      bf16x8 af[4];
#pragma unroll
      for (int m = 0; m < 4; m++)
        af[m] = *reinterpret_cast<const bf16x8*>(
            lA + (wr * 64 + m * 16 + l15) * BK + (((kk * 4 + lhi) ^ (l15 & 7)) * 8));
#pragma unroll
      for (int n = 0; n < 4; n++) {
        bf16x8 gf = *reinterpret_cast<const bf16x8*>(lG + (wc * 64 + n * 16 + l15) * BKP + (kk * 4 + lhi) * 8);
        bf16x8 uf = *reinterpret_cast<const bf16x8*>(lU + (wc * 64 + n * 16 + l15) * BKP + (kk * 4 + lhi) * 8);
#pragma unroll
        for (int m = 0; m < 4; m++) {
          accg[m][n] = __builtin_amdgcn_mfma_f32_16x16x32_bf16(af[m], gf, accg[m][n], 0, 0, 0);
          accu[m][n] = __builtin_amdgcn_mfma_f32_16x16x32_bf16(af[m], uf, accu[m][n], 0, 0, 0);
        }
      }
    }
  }

#pragma unroll
  for (int m = 0; m < 4; m++)
#pragma unroll
    for (int n = 0; n < 4; n++)
#pragma unroll
      for (int r2 = 0; r2 < 4; r2++) {
        float gv = accg[m][n][r2];
        float uv = accu[m][n][r2];
        float s = (gv / (1.f + __expf(-gv))) * uv;      // silu(g)*u
        int row = rt * BM + wr * 64 + m * 16 + lhi * 4 + r2;  // C: row=(lane>>4)*4+reg
        int col = i0 + wc * 64 + n * 16 + l15;                //    col=lane&15  [m89]
        act[(long)row * N + col] = __float2bfloat16(s);
      }
}

// ============ down GEMM: out = act @ Wd, Wd fp32 NATIVE [Kin][H] ============
__launch_bounds__(256, 2)
__global__ void gemm_down_kernel(const bf* __restrict__ A,
                                 const int* __restrict__ rows,
                                 const int* __restrict__ tile_expert,
                                 const int* __restrict__ n_tiles,
                                 const float* __restrict__ Wd,
                                 bf* __restrict__ outbuf, int Kin) {
  int rt = blockIdx.y;
  if (n_tiles && rt >= *n_tiles) return;
  int e = tile_expert ? tile_expert[rt] : 0;
  int h0 = blockIdx.x * BN;

  __shared__ bf lA[BM * BK];
  __shared__ bf lB[BN * BKP];
  __shared__ int rowsl[BM];

  int tid = threadIdx.x, w = tid >> 6, lane = tid & 63;
  int l15 = lane & 15, lhi = lane >> 4;
  int kg = tid >> 5, ng = tid & 31;
  int sswz = (((lane & 7) ^ (lane >> 3)) * 8);
  if (rows && tid < BM) rowsl[tid] = rows[rt * BM + tid];

  long aoff[4];
#pragma unroll
  for (int i = 0; i < 4; i++)
    aoff[i] = (long)(rt * BM + i * 32 + w * 8 + (lane >> 3)) * Kin + sswz;

  const float* bw = Wd + (long)e * Kin * H_DIM + h0 + ng * 4 + (long)kg * 8 * H_DIM;

  f32x4 acc[4][4];
  f32x4 z4 = {0.f, 0.f, 0.f, 0.f};
#pragma unroll
  for (int m = 0; m < 4; m++)
#pragma unroll
    for (int n = 0; n < 4; n++) acc[m][n] = z4;

  int wr = w >> 1, wc = w & 1;
  for (int kt = 0; kt < Kin; kt += BK) {
    float4 vb[8];
    const float* pb = bw + (long)kt * H_DIM;
#pragma unroll
    for (int j = 0; j < 8; j++) vb[j] = *reinterpret_cast<const float4*>(pb + (long)j * H_DIM);
    __syncthreads();
#pragma unroll
    for (int i = 0; i < 4; i++)
      gload16(A + aoff[i] + kt, lA + (i * 32 + w * 8) * BK);
#pragma unroll
    for (int c = 0; c < 4; c++) {
      union { bf16x8 x; bf s[8]; } ob;
#pragma unroll
      for (int j = 0; j < 8; j++)
        ob.s[j] = __float2bfloat16(((const float*)&vb[j])[c]);
      *reinterpret_cast<bf16x8*>(lB + (ng * 4 + c) * BKP + kg * 8) = ob.x;
    }
    __syncthreads();
#pragma unroll
    for (int kk = 0; kk < 2; kk++) {
      bf16x8 af[4];
#pragma unroll
      for (int m = 0; m < 4; m++)
        af[m] = *reinterpret_cast<const bf16x8*>(
            lA + (wr * 64 + m * 16 + l15) * BK + (((kk * 4 + lhi) ^ (l15 & 7)) * 8));
#pragma unroll
      for (int n = 0; n < 4; n++) {
        bf16x8 bfr = *reinterpret_cast<const bf16x8*>(lB + (wc * 64 + n * 16 + l15) * BKP + (kk * 4 + lhi) * 8);
#pragma unroll
        for (int m = 0; m < 4; m++)
          acc[m][n] = __builtin_amdgcn_mfma_f32_16x16x32_bf16(af[m], bfr, acc[m][n], 0, 0, 0);
      }
    }
  }

#pragma unroll
  for (int m = 0; m < 4; m++)
#pragma unroll
    for (int n = 0; n < 4; n++)
#pragma unroll
      for (int r2 = 0; r2 < 4; r2++) {
        int lrow = wr * 64 + m * 16 + lhi * 4 + r2;
        int col = h0 + wc * 64 + n * 16 + l15;
        float v = acc[m][n][r2];
        if (rows) {
          int p = rowsl[lrow];
          if (p >= 0) outbuf[(long)p * H_DIM + col] = __float2bfloat16(v);
        } else {
          outbuf[(long)(rt * BM + lrow) * H_DIM + col] = __float2bfloat16(v);
        }
      }
}

// ---------------- combine: out = shared + sum_k w_k * pair_k (fixed order => deterministic) ----
__global__ void combine_kernel(const bf* __restrict__ out_pair,
                               const bf* __restrict__ shared_out,
                               const float* __restrict__ topk_w,
                               float* __restrict__ out) {
  int idx = blockIdx.x * blockDim.x + threadIdx.x;
  int t = idx >> 11;   // H_DIM = 2048
  int h = idx & 2047;
  float acc = __bfloat162float(shared_out[idx]);
#pragma unroll
  for (int k = 0; k < 4; k++)
    acc += topk_w[t * 4 + k] * __bfloat162float(out_pair[(long)(t * 4 + k) * H_DIM + h]);
  out[idx] = acc;
}

extern "C" void kernel_launch(void* const* d_in, const int* in_sizes, int n_in,
                              void* d_out, int out_size, void* d_ws, size_t ws_size,
                              hipStream_t stream) {
  const float* x     = (const float*)d_in[0];
  const float* gw    = (const float*)d_in[1];
  const float* wgate = (const float*)d_in[2];
  const float* wup   = (const float*)d_in[3];
  const float* wdown = (const float*)d_in[4];
  const float* swg   = (const float*)d_in[5];
  const float* swu   = (const float*)d_in[6];
  const float* swd   = (const float*)d_in[7];
  float* out = (float*)d_out;

  char* ws = (char*)d_ws;
  size_t off = 0;
  auto alloc = [&](size_t bytes) {
    void* p = ws + off;
    off += (bytes + 255) & ~(size_t)255;
    return p;
  };

  bf* xb   = (bf*)alloc((size_t)T_TOK * H_DIM * 2);
  bf* act  = (bf*)alloc((size_t)MAXRT * BM * I_DIM * 2);      // padded-slot rows
  bf* sact = (bf*)alloc((size_t)T_TOK * IS_DIM * 2);
  bf* outp = (bf*)alloc((size_t)T_TOK * K_TOP * H_DIM * 2);   // per (t,k) expert output
  bf* sout = (bf*)alloc((size_t)T_TOK * H_DIM * 2);
  int*   topk_idx = (int*)alloc(T_TOK * K_TOP * 4);
  float* topk_w   = (float*)alloc(T_TOK * K_TOP * 4);
  int*   rowsbuf  = (int*)alloc(MAXRT * BM * 4);
  int*   tile_exp = (int*)alloc(MAXRT * 4);
  int*   n_tiles  = (int*)alloc(64);
  (void)ws_size; (void)in_sizes; (void)n_in; (void)out_size;

  hipLaunchKernelGGL(cvt_x_kernel, dim3(T_TOK * H_DIM / 1024), dim3(256), 0, stream, x, xb);
  hipLaunchKernelGGL(gate_topk_kernel, dim3(T_TOK), dim3(64), 0, stream, x, gw, topk_idx, topk_w);
  hipLaunchKernelGGL(build_lists_kernel, dim3(1), dim3(256), 0, stream, topk_idx, rowsbuf, tile_exp, n_tiles);

  // routed gate+up -> act      (B = wgate/wup fp32 native [H][I])
  hipLaunchKernelGGL(gemm_gateup_kernel, dim3(I_DIM / BN, MAXRT), dim3(256), 0, stream,
                     xb, rowsbuf, tile_exp, n_tiles, wgate, wup, act, I_DIM);
  // shared gate+up -> sact     (B = sw_gate/sw_up fp32 native [H][IS])
  hipLaunchKernelGGL(gemm_gateup_kernel, dim3(IS_DIM / BN, T_TOK / BM), dim3(256), 0, stream,
                     xb, nullptr, nullptr, nullptr, swg, swu, sact, IS_DIM);
  // routed down -> outp        (B = wdown fp32 native [I][H])
  hipLaunchKernelGGL(gemm_down_kernel, dim3(H_DIM / BN, MAXRT), dim3(256), 0, stream,
                     act, rowsbuf, tile_exp, n_tiles, wdown, outp, I_DIM);
  // shared down -> sout        (B = sw_down fp32 native [IS][H])
  hipLaunchKernelGGL(gemm_down_kernel, dim3(H_DIM / BN, T_TOK / BM), dim3(256), 0, stream,
                     sact, nullptr, nullptr, nullptr, swd, sout, IS_DIM);

  hipLaunchKernelGGL(combine_kernel, dim3(T_TOK * H_DIM / 256), dim3(256), 0, stream,
                     outp, sout, topk_w, out);
}